// Round 9
// baseline (160.029 us; speedup 1.0000x reference)
//
#include <hip/hip_runtime.h>

// IRNN 8-direction scan. x: [8,32,256,256] f32. Outputs (concat order):
// 0 up, 1 right, 2 down, 3 left, 4 zuoxia, 5 youxia, 6 zuoshang(==zuoxia), 7 youshang.
//
// Round-9 PROBE: R6 verbatim (124.8us best), but horizontal launched TWICE
// (idempotent; second launch rewrites identical bytes). dur - 124.8 = t_h,
// giving the vertical/horizontal time split that rocprof top-5 (clogged by
// 315us harness fills) cannot show.

namespace {
constexpr int HH = 256;
constexpr int WW = 256;
constexpr int PLANE = HH * WW;                       // 65536
constexpr size_t TEN = (size_t)PLANE * 256;          // elems per output tensor

__device__ __forceinline__ float relu_f(float a) { return fmaxf(a, 0.0f); }

typedef float v4f __attribute__((ext_vector_type(4)));

__device__ __forceinline__ void nt_store4(float* p, const float4& v) {
    v4f t; t.x = v.x; t.y = v.y; t.z = v.z; t.w = v.w;
    __builtin_nontemporal_store(t, (v4f*)p);
}
} // namespace

// ---------- vertical family: one wave (64 threads) per (role, plane) ----------
// role 0: down -> out2 ; 1: up -> out0 ; 2: zuoxia -> out4+out6 ;
// role 3: youxia -> out5 ; 4: youshang -> out7
__global__ __launch_bounds__(64) void irnn_vertical(
    const float* __restrict__ x, float* __restrict__ out,
    const float* __restrict__ wup_p, const float* __restrict__ wdn_p)
{
    const int bid = blockIdx.x;
    const int role = bid >> 8;       // 5 roles x 256 planes
    const int plane = bid & 255;
    const int t = threadIdx.x;       // lane owns columns 4t..4t+3

    const float* xp = x + (size_t)plane * PLANE + t * 4;

    if (role == 0) {                 // top_down: out[h]=relu(out[h-1]*wd+x[h])
        const float wd = *wdn_p;
        float* op = out + 2 * TEN + (size_t)plane * PLANE + t * 4;
        float4 c = *(const float4*)xp;
        nt_store4(op, c);
        for (int h = 1; h < HH; ++h) {
            float4 v = *(const float4*)(xp + h * WW);
            c.x = relu_f(c.x * wd + v.x);
            c.y = relu_f(c.y * wd + v.y);
            c.z = relu_f(c.z * wd + v.z);
            c.w = relu_f(c.w * wd + v.w);
            nt_store4(op + h * WW, c);
        }
    } else if (role == 1) {          // top_up: out[h]=relu(out[h+1]*wu+x[h])
        const float wu = *wup_p;
        float* op = out + 0 * TEN + (size_t)plane * PLANE + t * 4;
        float4 c = *(const float4*)(xp + (HH - 1) * WW);
        nt_store4(op + (HH - 1) * WW, c);
        for (int h = HH - 2; h >= 0; --h) {
            float4 v = *(const float4*)(xp + h * WW);
            c.x = relu_f(c.x * wu + v.x);
            c.y = relu_f(c.y * wu + v.y);
            c.z = relu_f(c.z * wu + v.z);
            c.w = relu_f(c.w * wu + v.w);
            nt_store4(op + h * WW, c);
        }
    } else if (role == 2) {          // zuoxia/zuoshang: out[h][w]=relu(out[h-1][w-1]*wd+x[h][w])
        const float wd = *wdn_p;
        float* o4 = out + 4 * TEN + (size_t)plane * PLANE + t * 4;
        float* o6 = out + 6 * TEN + (size_t)plane * PLANE + t * 4;
        float4 c = *(const float4*)xp;   // h=0 row pass-through
        nt_store4(o4, c);
        nt_store4(o6, c);
        for (int h = 1; h < HH; ++h) {
            float4 v = *(const float4*)(xp + h * WW);
            float pw = __shfl_up(c.w, 1);     // lane t-1's element 3 == column 4t-1
            float4 n;
            n.x = (t == 0) ? v.x : relu_f(pw * wd + v.x);   // w==0 pass-through
            n.y = relu_f(c.x * wd + v.y);
            n.z = relu_f(c.y * wd + v.z);
            n.w = relu_f(c.z * wd + v.w);
            nt_store4(o4 + h * WW, n);
            nt_store4(o6 + h * WW, n);
            c = n;
        }
    } else if (role == 3) {          // youxia: out[h][w]=relu(out[h-1][w+1]*wd+x[h][w])
        const float wd = *wdn_p;
        float* o5 = out + 5 * TEN + (size_t)plane * PLANE + t * 4;
        float4 c = *(const float4*)xp;   // h=0 row pass-through
        nt_store4(o5, c);
        for (int h = 1; h < HH; ++h) {
            float4 v = *(const float4*)(xp + h * WW);
            float nx = __shfl_down(c.x, 1);   // lane t+1's element 0 == column 4t+4
            float4 n;
            n.x = relu_f(c.y * wd + v.x);
            n.y = relu_f(c.z * wd + v.y);
            n.z = relu_f(c.w * wd + v.z);
            n.w = (t == 63) ? v.w : relu_f(nx * wd + v.w);  // w==255 pass-through
            nt_store4(o5 + h * WW, n);
            c = n;
        }
    } else {                         // youshang: out[h][w]=relu(out[h+1][w-1]*wd+x[h][w])
        const float wd = *wdn_p;
        float* o7 = out + 7 * TEN + (size_t)plane * PLANE + t * 4;
        float4 c = *(const float4*)(xp + (HH - 1) * WW);   // h=255 pass-through
        nt_store4(o7 + (HH - 1) * WW, c);
        for (int h = HH - 2; h >= 0; --h) {
            float4 v = *(const float4*)(xp + h * WW);
            float pw = __shfl_up(c.w, 1);
            float4 n;
            n.x = (t == 0) ? v.x : relu_f(pw * wd + v.x);   // w==0 pass-through
            n.y = relu_f(c.x * wd + v.y);
            n.z = relu_f(c.y * wd + v.z);
            n.w = relu_f(c.z * wd + v.w);
            nt_store4(o7 + h * WW, n);
            c = n;
        }
    }
}

// ---------- horizontal family: right (out1) and left (out3) ----------
// block = 64 threads = 1 wave; each block owns 64 global rows.
// LDS-staged 64x32 chunks: coalesced global <-> LDS, per-thread scan in LDS.
__global__ __launch_bounds__(64) void irnn_horizontal(
    const float* __restrict__ x, float* __restrict__ out,
    const float* __restrict__ wlf_p, const float* __restrict__ wrt_p)
{
    __shared__ float xs[64][33];
    __shared__ float os[64][33];

    const int bid = blockIdx.x;
    const int dir = bid >> 10;        // 0: right, 1: left
    const int rb  = bid & 1023;       // row-block index (1024 blocks of 64 rows)
    const size_t row0 = (size_t)rb * 64;
    const int t = threadIdx.x;
    const int lrow = t >> 3;          // load/store mapping: 8 lanes per row
    const int lcol = (t & 7) * 4;

    const float w = dir ? *wlf_p : *wrt_p;
    float* op = out + (size_t)(dir ? 3 : 1) * TEN;

    float carry = 0.0f;
    for (int ci = 0; ci < 8; ++ci) {
        const int cw = dir ? (7 - ci) : ci;   // chunk order follows scan direction
        const int wbase = cw * 32;

        // load 64 rows x 32 cols (8 passes, 8 rows/pass, 128B/row segments)
        for (int p = 0; p < 8; ++p) {
            const int r = p * 8 + lrow;
            float4 v = *(const float4*)(x + (row0 + r) * WW + wbase + lcol);
            *(float4*)&xs[r][lcol] = v;
        }
        __syncthreads();

        // per-thread scan of own row t within the chunk
        if (dir == 0) {
            for (int j = 0; j < 32; ++j) {
                const float v = xs[t][j];
                const int wg = wbase + j;
                const float o = (wg == 0) ? v : relu_f(carry * w + v);
                carry = o;
                os[t][j] = o;
            }
        } else {
            for (int j = 31; j >= 0; --j) {
                const float v = xs[t][j];
                const int wg = wbase + j;
                const float o = (wg == WW - 1) ? v : relu_f(carry * w + v);
                carry = o;
                os[t][j] = o;
            }
        }
        __syncthreads();

        // coalesced writeout (non-temporal)
        for (int p = 0; p < 8; ++p) {
            const int r = p * 8 + lrow;
            float4 v = *(const float4*)&os[r][lcol];
            nt_store4(op + (row0 + r) * WW + wbase + lcol, v);
        }
        __syncthreads();
    }
}

extern "C" void kernel_launch(void* const* d_in, const int* in_sizes, int n_in,
                              void* d_out, int out_size, void* d_ws, size_t ws_size,
                              hipStream_t stream) {
    const float* x      = (const float*)d_in[0];
    const float* w_up   = (const float*)d_in[1];
    const float* w_down = (const float*)d_in[2];
    const float* w_left = (const float*)d_in[3];
    const float* w_right= (const float*)d_in[4];
    float* out = (float*)d_out;

    hipLaunchKernelGGL(irnn_vertical, dim3(5 * 256), dim3(64), 0, stream,
                       x, out, w_up, w_down);
    hipLaunchKernelGGL(irnn_horizontal, dim3(2 * 1024), dim3(64), 0, stream,
                       x, out, w_left, w_right);
    // PROBE: second identical horizontal launch (idempotent) to measure t_h.
    hipLaunchKernelGGL(irnn_horizontal, dim3(2 * 1024), dim3(64), 0, stream,
                       x, out, w_left, w_right);
}

// Round 10
// 124.323 us; speedup vs baseline: 1.2872x; 1.2872x over previous
//
#include <hip/hip_runtime.h>

// IRNN 8-direction scan. x: [8,32,256,256] f32. Outputs (concat order):
// 0 up, 1 right, 2 down, 3 left, 4 zuoxia, 5 youxia, 6 zuoshang(==zuoxia), 7 youshang.
//
// Round-10: R6 base + ONE change: role 2 (zuoxia, formerly 2 stores/iter into
// out4 AND out6) is split into two roles that duplicate the cheap compute and
// store ONE tensor each. Balances store load across 6 uniform vertical roles
// (1536 blocks, 6 waves/CU) and removes the role-2 straggler tail.
//   vertical roles: 0 down->out2, 1 up->out0, 2 zuoxia->out4, 3 zuoxia->out6,
//                   4 youxia->out5, 5 youshang->out7

namespace {
constexpr int HH = 256;
constexpr int WW = 256;
constexpr int PLANE = HH * WW;                       // 65536
constexpr size_t TEN = (size_t)PLANE * 256;          // elems per output tensor

__device__ __forceinline__ float relu_f(float a) { return fmaxf(a, 0.0f); }

typedef float v4f __attribute__((ext_vector_type(4)));

__device__ __forceinline__ void nt_store4(float* p, const float4& v) {
    v4f t; t.x = v.x; t.y = v.y; t.z = v.z; t.w = v.w;
    __builtin_nontemporal_store(t, (v4f*)p);
}
} // namespace

// ---------- vertical family: one wave (64 threads) per (role, plane) ----------
__global__ __launch_bounds__(64) void irnn_vertical(
    const float* __restrict__ x, float* __restrict__ out,
    const float* __restrict__ wup_p, const float* __restrict__ wdn_p)
{
    const int bid = blockIdx.x;
    const int role = bid >> 8;       // 6 roles x 256 planes
    const int plane = bid & 255;
    const int t = threadIdx.x;       // lane owns columns 4t..4t+3

    const float* xp = x + (size_t)plane * PLANE + t * 4;

    if (role == 0) {                 // top_down: out[h]=relu(out[h-1]*wd+x[h])
        const float wd = *wdn_p;
        float* op = out + 2 * TEN + (size_t)plane * PLANE + t * 4;
        float4 c = *(const float4*)xp;
        nt_store4(op, c);
        for (int h = 1; h < HH; ++h) {
            float4 v = *(const float4*)(xp + h * WW);
            c.x = relu_f(c.x * wd + v.x);
            c.y = relu_f(c.y * wd + v.y);
            c.z = relu_f(c.z * wd + v.z);
            c.w = relu_f(c.w * wd + v.w);
            nt_store4(op + h * WW, c);
        }
    } else if (role == 1) {          // top_up: out[h]=relu(out[h+1]*wu+x[h])
        const float wu = *wup_p;
        float* op = out + 0 * TEN + (size_t)plane * PLANE + t * 4;
        float4 c = *(const float4*)(xp + (HH - 1) * WW);
        nt_store4(op + (HH - 1) * WW, c);
        for (int h = HH - 2; h >= 0; --h) {
            float4 v = *(const float4*)(xp + h * WW);
            c.x = relu_f(c.x * wu + v.x);
            c.y = relu_f(c.y * wu + v.y);
            c.z = relu_f(c.z * wu + v.z);
            c.w = relu_f(c.w * wu + v.w);
            nt_store4(op + h * WW, c);
        }
    } else if (role == 2 || role == 3) {   // zuoxia -> out4 (role2) / out6 (role3)
        const float wd = *wdn_p;
        float* op = out + (role == 2 ? 4 : 6) * TEN + (size_t)plane * PLANE + t * 4;
        float4 c = *(const float4*)xp;   // h=0 row pass-through
        nt_store4(op, c);
        for (int h = 1; h < HH; ++h) {
            float4 v = *(const float4*)(xp + h * WW);
            float pw = __shfl_up(c.w, 1);     // lane t-1's element 3 == column 4t-1
            float4 n;
            n.x = (t == 0) ? v.x : relu_f(pw * wd + v.x);   // w==0 pass-through
            n.y = relu_f(c.x * wd + v.y);
            n.z = relu_f(c.y * wd + v.z);
            n.w = relu_f(c.z * wd + v.w);
            nt_store4(op + h * WW, n);
            c = n;
        }
    } else if (role == 4) {          // youxia: out[h][w]=relu(out[h-1][w+1]*wd+x[h][w])
        const float wd = *wdn_p;
        float* o5 = out + 5 * TEN + (size_t)plane * PLANE + t * 4;
        float4 c = *(const float4*)xp;   // h=0 row pass-through
        nt_store4(o5, c);
        for (int h = 1; h < HH; ++h) {
            float4 v = *(const float4*)(xp + h * WW);
            float nx = __shfl_down(c.x, 1);   // lane t+1's element 0 == column 4t+4
            float4 n;
            n.x = relu_f(c.y * wd + v.x);
            n.y = relu_f(c.z * wd + v.y);
            n.z = relu_f(c.w * wd + v.z);
            n.w = (t == 63) ? v.w : relu_f(nx * wd + v.w);  // w==255 pass-through
            nt_store4(o5 + h * WW, n);
            c = n;
        }
    } else {                         // youshang: out[h][w]=relu(out[h+1][w-1]*wd+x[h][w])
        const float wd = *wdn_p;
        float* o7 = out + 7 * TEN + (size_t)plane * PLANE + t * 4;
        float4 c = *(const float4*)(xp + (HH - 1) * WW);   // h=255 pass-through
        nt_store4(o7 + (HH - 1) * WW, c);
        for (int h = HH - 2; h >= 0; --h) {
            float4 v = *(const float4*)(xp + h * WW);
            float pw = __shfl_up(c.w, 1);
            float4 n;
            n.x = (t == 0) ? v.x : relu_f(pw * wd + v.x);   // w==0 pass-through
            n.y = relu_f(c.x * wd + v.y);
            n.z = relu_f(c.y * wd + v.z);
            n.w = relu_f(c.z * wd + v.w);
            nt_store4(o7 + h * WW, n);
            c = n;
        }
    }
}

// ---------- horizontal family: right (out1) and left (out3) ----------
__global__ __launch_bounds__(64) void irnn_horizontal(
    const float* __restrict__ x, float* __restrict__ out,
    const float* __restrict__ wlf_p, const float* __restrict__ wrt_p)
{
    __shared__ float xs[64][33];
    __shared__ float os[64][33];

    const int bid = blockIdx.x;
    const int dir = bid >> 10;        // 0: right, 1: left
    const int rb  = bid & 1023;       // row-block index (1024 blocks of 64 rows)
    const size_t row0 = (size_t)rb * 64;
    const int t = threadIdx.x;
    const int lrow = t >> 3;          // load/store mapping: 8 lanes per row
    const int lcol = (t & 7) * 4;

    const float w = dir ? *wlf_p : *wrt_p;
    float* op = out + (size_t)(dir ? 3 : 1) * TEN;

    float carry = 0.0f;
    for (int ci = 0; ci < 8; ++ci) {
        const int cw = dir ? (7 - ci) : ci;   // chunk order follows scan direction
        const int wbase = cw * 32;

        // load 64 rows x 32 cols (8 passes, 8 rows/pass, 128B/row segments)
        for (int p = 0; p < 8; ++p) {
            const int r = p * 8 + lrow;
            float4 v = *(const float4*)(x + (row0 + r) * WW + wbase + lcol);
            *(float4*)&xs[r][lcol] = v;
        }
        __syncthreads();

        // per-thread scan of own row t within the chunk
        if (dir == 0) {
            for (int j = 0; j < 32; ++j) {
                const float v = xs[t][j];
                const int wg = wbase + j;
                const float o = (wg == 0) ? v : relu_f(carry * w + v);
                carry = o;
                os[t][j] = o;
            }
        } else {
            for (int j = 31; j >= 0; --j) {
                const float v = xs[t][j];
                const int wg = wbase + j;
                const float o = (wg == WW - 1) ? v : relu_f(carry * w + v);
                carry = o;
                os[t][j] = o;
            }
        }
        __syncthreads();

        // coalesced writeout (non-temporal)
        for (int p = 0; p < 8; ++p) {
            const int r = p * 8 + lrow;
            float4 v = *(const float4*)&os[r][lcol];
            nt_store4(op + (row0 + r) * WW + wbase + lcol, v);
        }
        __syncthreads();
    }
}

extern "C" void kernel_launch(void* const* d_in, const int* in_sizes, int n_in,
                              void* d_out, int out_size, void* d_ws, size_t ws_size,
                              hipStream_t stream) {
    const float* x      = (const float*)d_in[0];
    const float* w_up   = (const float*)d_in[1];
    const float* w_down = (const float*)d_in[2];
    const float* w_left = (const float*)d_in[3];
    const float* w_right= (const float*)d_in[4];
    float* out = (float*)d_out;

    hipLaunchKernelGGL(irnn_vertical, dim3(6 * 256), dim3(64), 0, stream,
                       x, out, w_up, w_down);
    hipLaunchKernelGGL(irnn_horizontal, dim3(2 * 1024), dim3(64), 0, stream,
                       x, out, w_left, w_right);
}